// Round 16
// baseline (542.784 us; speedup 1.0000x reference)
//
#include <hip/hip_runtime.h>
#include <hip/hip_bf16.h>

typedef __attribute__((ext_vector_type(8))) short bf16x8;
typedef __attribute__((ext_vector_type(4))) float f32x4;
typedef __attribute__((ext_vector_type(16))) float f32x16;
typedef __attribute__((ext_vector_type(8))) unsigned short u16x8;
typedef unsigned short ushort_t;

#define DEVFN static __device__ __forceinline__

DEVFN ushort_t f2bf(float f) {
  unsigned int u = __builtin_bit_cast(unsigned int, f);
  u += 0x7FFFu + ((u >> 16) & 1u);   // RNE
  return (ushort_t)(u >> 16);
}

DEVFN unsigned int cvtpk_bf16(float lo, float hi) {
  unsigned int r;
  asm("v_cvt_pk_bf16_f32 %0, %1, %2" : "=v"(r) : "v"(lo), "v"(hi));
  return r;
}

// async global->LDS, 16B per lane; LDS dest is wave-uniform base + lane*16
DEVFN void gload_lds16(const void* g, void* l) {
  __builtin_amdgcn_global_load_lds(
      (const __attribute__((address_space(1))) void*)g,
      (__attribute__((address_space(3))) void*)l, 16, 0, 0);
}

// bijective XCD swizzle (m204): consecutive post-swizzle ids share an XCD
DEVFN int xcd_swz(int bid, int nwg) {
  int q = nwg >> 3, r = nwg & 7;
  int xcd = bid & 7, u = bid >> 3;
  return (xcd < r ? xcd * (q + 1) : r * (q + 1) + (xcd - r) * q) + u;
}

// ---------------------------------------------------------------- prep ----
__global__ void k_prep_w(const float* __restrict__ qkv_w, const float* __restrict__ proj_w,
                         const float* __restrict__ q_bias, const float* __restrict__ v_bias,
                         ushort_t* __restrict__ qkv_wb, ushort_t* __restrict__ proj_wb,
                         float* __restrict__ qkv_bias) {
  int gid = blockIdx.x * blockDim.x + threadIdx.x;
  int stride = gridDim.x * blockDim.x;
  for (int i = gid; i < 1152 * 384; i += stride) qkv_wb[i] = f2bf(qkv_w[i]);
  for (int i = gid; i < 384 * 384; i += stride) proj_wb[i] = f2bf(proj_w[i]);
  for (int i = gid; i < 1152; i += stride)
    qkv_bias[i] = (i < 384) ? q_bias[i] : ((i < 768) ? 0.f : v_bias[i - 768]);
}

// x (fp32) -> bf16, vectorized
__global__ void k_xb(const float* __restrict__ x, ushort_t* __restrict__ xb, long n4) {
  long gid = (long)blockIdx.x * blockDim.x + threadIdx.x;
  long stride = (long)gridDim.x * blockDim.x;
  for (long i = gid; i < n4; i += stride) {
    float4 v = reinterpret_cast<const float4*>(x)[i];
    unsigned long long pk = (unsigned long long)f2bf(v.x) |
                            ((unsigned long long)f2bf(v.y) << 16) |
                            ((unsigned long long)f2bf(v.z) << 32) |
                            ((unsigned long long)f2bf(v.w) << 48);
    reinterpret_cast<unsigned long long*>(xb)[i] = pk;
  }
}

// CPB MLP: one block (64 threads) per table row; block 169 does logit scales
__global__ void k_prep_cpb(const float* __restrict__ rel_table, const float* __restrict__ cpb_w1,
                           const float* __restrict__ cpb_b1, const float* __restrict__ cpb_w2,
                           const float* __restrict__ logit_scale,
                           float* __restrict__ tbl, float* __restrict__ ls) {
  int lane = threadIdx.x;
  if (blockIdx.x == 169) {
    if (lane < 12) ls[lane] = __expf(fminf(logit_scale[lane], 4.605170185988092f)); // log(100)
    return;
  }
  int row = blockIdx.x;
  float t0 = rel_table[row * 2 + 0], t1 = rel_table[row * 2 + 1];
  float acc[12];
#pragma unroll
  for (int h = 0; h < 12; h++) acc[h] = 0.f;
  for (int j = lane; j < 512; j += 64) {
    float hj = fmaxf(cpb_w1[j * 2] * t0 + cpb_w1[j * 2 + 1] * t1 + cpb_b1[j], 0.f);
#pragma unroll
    for (int h = 0; h < 12; h++) acc[h] += cpb_w2[h * 512 + j] * hj;
  }
#pragma unroll
  for (int h = 0; h < 12; h++) {
    float v = acc[h];
    v += __shfl_xor(v, 1);  v += __shfl_xor(v, 2);  v += __shfl_xor(v, 4);
    v += __shfl_xor(v, 8);  v += __shfl_xor(v, 16); v += __shfl_xor(v, 32);
    if (lane == 0) tbl[row * 12 + h] = v;
  }
}

// comb[(w*12+h)*2404 + i*49+j] = 16*sigmoid(tbl[rel_index[ij]][h]) + mask[w][ij]
__global__ void k_prep_comb(const float* __restrict__ tbl, const int* __restrict__ rel_index,
                            const float* __restrict__ mask, float* __restrict__ comb) {
  int gid = blockIdx.x * blockDim.x + threadIdx.x;
  if (gid >= 64 * 12 * 2401) return;
  int ij = gid % 2401;
  int h = (gid / 2401) % 12;
  int w = gid / (2401 * 12);
  float t = tbl[rel_index[ij] * 12 + h];
  comb[(size_t)(w * 12 + h) * 2404 + ij] = 16.f / (1.f + __expf(-t)) + mask[w * 2401 + ij];
}

// ------------------------------------------------- K1: qkv GEMM + norm ----
// C[M x 1152] = xb[M x 384] * qkv_w^T (bf16 in), + bias; q rows L2-normalized
// AND scaled by per-head logit scale; k rows L2-normalized. bf16 out.
// R6 inner structure (2x2 waves 64x64, 32 KB single-buffer LDS, gload+XOR
// swizzle) with in-block n-serialization: each block owns one m-tile and
// loops the 9 n-tiles, so A-tile re-stages hit L2 and prologues amortize.
__global__ void __launch_bounds__(256, 4) k_qkv(const ushort_t* __restrict__ xb,
                                                const ushort_t* __restrict__ wb,
                                                const float* __restrict__ bias,
                                                const float* __restrict__ lsb,
                                                ushort_t* __restrict__ qkvn, int nmb) {
  __shared__ __align__(16) ushort_t As[128][64];
  __shared__ __align__(16) ushort_t Bs[128][64];
  const int tid = threadIdx.x;
  const int lane = tid & 63, wid = tid >> 6;
  const int wm = wid >> 1, wn = wid & 1;   // 2 x 2 wave grid, each 64 x 64
  const int l15 = lane & 15, g = lane >> 4;
  const int mblk = xcd_swz(blockIdx.x, nmb);
  const int m0 = mblk * 128;

  // staging geometry (loop-invariant): chunk i = wid*64 + lane + it*256
  const int rb_ = (wid << 3) + (lane >> 3);           // row base (it=0)
  const int cg_ = (lane & 7) ^ (rb_ & 7);             // pre-swizzled src chunk
  const size_t so_ = (size_t)rb_ * 384 + cg_ * 8;
  const int lo_ = wid * 512;                          // wave-uniform LDS base

#define QKV_STAGE(n0v, kk)                                                   \
  {                                                                          \
    const ushort_t* ga = xb + (size_t)m0 * 384 + (kk) * 64;                  \
    const ushort_t* gb = wb + (size_t)(n0v) * 384 + (kk) * 64;               \
    _Pragma("unroll")                                                        \
    for (int it = 0; it < 4; it++) {                                         \
      gload_lds16(ga + so_ + (size_t)it * 12288, &As[0][0] + lo_ + it * 2048);\
      gload_lds16(gb + so_ + (size_t)it * 12288, &Bs[0][0] + lo_ + it * 2048);\
    }                                                                        \
  }

  for (int nt = 0; nt < 9; nt++) {
    const int n0 = nt * 128;
    f32x4 acc[4][4] = {};
    for (int kk = 0; kk < 6; kk++) {
      __syncthreads();
      QKV_STAGE(n0, kk);
      __syncthreads();
#pragma unroll
      for (int ks = 0; ks < 64; ks += 32) {
        const int cxor = (ks >> 3) + g;
        bf16x8 a[4], b[4];
#pragma unroll
        for (int mi = 0; mi < 4; mi++) {
          int row = wm * 64 + mi * 16 + l15;
          a[mi] = *reinterpret_cast<const bf16x8*>(&As[row][(cxor ^ (row & 7)) * 8]);
        }
#pragma unroll
        for (int ni = 0; ni < 4; ni++) {
          int row = wn * 64 + ni * 16 + l15;
          b[ni] = *reinterpret_cast<const bf16x8*>(&Bs[row][(cxor ^ (row & 7)) * 8]);
        }
#pragma unroll
        for (int mi = 0; mi < 4; mi++)
#pragma unroll
          for (int ni = 0; ni < 4; ni++)
            acc[mi][ni] = __builtin_amdgcn_mfma_f32_16x16x32_bf16(a[mi], b[ni], acc[mi][ni], 0, 0, 0);
      }
    }
    // epilogue for this n-tile: bias, per-32-col head-group L2 norm
    const int colbase = n0 + wn * 64;        // 64-aligned: never crosses q/k/v
    const int which = colbase / 384;         // 0=q 1=k 2=v
    const float scl0 = (which == 0) ? lsb[(colbase >> 5)] : 1.f;
    const float scl1 = (which == 0) ? lsb[(colbase >> 5) + 1] : 1.f;
    float bs[4];
#pragma unroll
    for (int ni = 0; ni < 4; ni++) bs[ni] = bias[colbase + ni * 16 + l15];
#pragma unroll
    for (int mi = 0; mi < 4; mi++) {
#pragma unroll
      for (int r = 0; r < 4; r++) {
        float v[4];
#pragma unroll
        for (int ni = 0; ni < 4; ni++) v[ni] = acc[mi][ni][r] + bs[ni];
        if (which < 2) {
          float ss0 = v[0] * v[0] + v[1] * v[1];
          float ss1 = v[2] * v[2] + v[3] * v[3];
          ss0 += __shfl_xor(ss0, 1); ss1 += __shfl_xor(ss1, 1);
          ss0 += __shfl_xor(ss0, 2); ss1 += __shfl_xor(ss1, 2);
          ss0 += __shfl_xor(ss0, 4); ss1 += __shfl_xor(ss1, 4);
          ss0 += __shfl_xor(ss0, 8); ss1 += __shfl_xor(ss1, 8);
          float rn0 = scl0 / (sqrtf(ss0) + 1e-6f);
          float rn1 = scl1 / (sqrtf(ss1) + 1e-6f);
          v[0] *= rn0; v[1] *= rn0; v[2] *= rn1; v[3] *= rn1;
        }
        int row = m0 + wm * 64 + mi * 16 + g * 4 + r;
        size_t base = (size_t)row * 1152 + colbase + l15;
#pragma unroll
        for (int ni = 0; ni < 4; ni++) qkvn[base + ni * 16] = f2bf(v[ni]);
      }
    }
  }
#undef QKV_STAGE
}

// ------------------------------------------- K2a: attention per (win,h) ----
// 4-wave blocks; waves handle 4 windows sharing the same shift-window w.
// ILP: all global loads issued before comb staging; comb in padded [50][52]
// LDS (ds_read_b128 bias adds); float4 comb staging (stride-2404 source).
__global__ void __launch_bounds__(256, 4) k_attn(const ushort_t* __restrict__ qkvn,
                                                 const float* __restrict__ comb,
                                                 ushort_t* __restrict__ attn,
                                                 int win_base, int nk) {
  __shared__ __align__(16) float comb_s[50][52];
  __shared__ __align__(16) ushort_t Vt[4][32][72];
  const int tid = threadIdx.x;
  const int lane = tid & 63, wv = tid >> 6;
  const int l31 = lane & 31, hi = lane >> 5;
  const int h = blockIdx.y;
  const int wloc = blockIdx.x & 63;
  const int k = (blockIdx.x >> 6) * 4 + wv;
  const bool active = k < nk;
  const int w_abs = (win_base + wloc) & 63;
  const size_t rowbase = (size_t)(wloc + 64 * k) * 49;

  // ---- issue ALL global loads first (ILP: ~12x16B in flight per lane) ----
  u16x8 vreg[4];
  bf16x8 qf[2][2], kf[2][2];
  if (active) {
#pragma unroll
    for (int pass = 0; pass < 4; pass++) {
      int t = pass * 16 + (lane >> 2);
      int d0 = (lane & 3) * 8;
      u16x8 v = {};
      if (t < 49)
        v = *reinterpret_cast<const u16x8*>(&qkvn[(rowbase + t) * 1152 + 768 + h * 32 + d0]);
      vreg[pass] = v;
    }
#pragma unroll
    for (int b = 0; b < 2; b++) {
      int t = b * 32 + l31; if (t > 48) t = 48;
      size_t rb = (rowbase + t) * 1152 + h * 32 + hi * 8;
#pragma unroll
      for (int ks = 0; ks < 2; ks++) {
        qf[b][ks] = *reinterpret_cast<const bf16x8*>(&qkvn[rb + ks * 16]);
        kf[b][ks] = *reinterpret_cast<const bf16x8*>(&qkvn[rb + 384 + ks * 16]);
      }
    }
  }

  // ---- comb stage: float4 global loads, scatter into padded layout ----
  {
    const float* ct = comb + (size_t)(w_abs * 12 + h) * 2404;
    for (int i4 = tid; i4 < 600; i4 += 256) {
      float4 v = *reinterpret_cast<const float4*>(&ct[i4 * 4]);
      int e = i4 * 4;
      comb_s[(e + 0) / 49][(e + 0) % 49] = v.x;
      comb_s[(e + 1) / 49][(e + 1) % 49] = v.y;
      comb_s[(e + 2) / 49][(e + 2) % 49] = v.z;
      comb_s[(e + 3) / 49][(e + 3) % 49] = v.w;
    }
    if (tid == 0) comb_s[48][48] = ct[2400];
  }
  // ---- Vt LDS writes (waitcnt for vreg hides under comb staging) ----
  if (active) {
#pragma unroll
    for (int pass = 0; pass < 4; pass++) {
      int t = pass * 16 + (lane >> 2);
      int d0 = (lane & 3) * 8;
#pragma unroll
      for (int j = 0; j < 8; j++) Vt[wv][d0 + j][t] = vreg[pass][j];
    }
  }
  __syncthreads();
  if (!active) return;

  // S'[a][b] = K_a · Q_b^T : lane owns col qt = b*32+l31, rows kt = a*32+crow(r,hi)
  f32x16 S[2][2] = {};
#pragma unroll
  for (int a = 0; a < 2; a++)
#pragma unroll
    for (int b = 0; b < 2; b++) {
      S[a][b] = __builtin_amdgcn_mfma_f32_32x32x16_bf16(kf[a][0], qf[b][0], S[a][b], 0, 0, 0);
      S[a][b] = __builtin_amdgcn_mfma_f32_32x32x16_bf16(kf[a][1], qf[b][1], S[a][b], 0, 0, 0);
    }

#pragma unroll
  for (int b = 0; b < 2; b++) {
    const int qt = b * 32 + l31;
    const bool qok = qt < 49;
    const int qi = qok ? qt : 48;
    // bias add + mask + row max; comb read as f32x4 (rows 16B-aligned)
    float m = -3.0e38f;
#pragma unroll
    for (int a = 0; a < 2; a++)
#pragma unroll
      for (int rq = 0; rq < 4; rq++) {
        f32x4 ch = *reinterpret_cast<const f32x4*>(&comb_s[qi][a * 32 + rq * 8 + hi * 4]);
#pragma unroll
        for (int j = 0; j < 4; j++) {
          int r = rq * 4 + j;
          int kt = a * 32 + rq * 8 + hi * 4 + j;
          float v = (qok && kt < 49) ? (S[a][b][r] + ch[j]) : -3.0e38f;
          S[a][b][r] = v;
          m = fmaxf(m, v);
        }
      }
    m = fmaxf(m, __shfl_xor(m, 32));
    float s = 0.f;
#pragma unroll
    for (int a = 0; a < 2; a++)
#pragma unroll
      for (int r = 0; r < 16; r++) {
        float e = __expf(S[a][b][r] - m);
        S[a][b][r] = e;
        s += e;
      }
    s += __shfl_xor(s, 32);
    const float inv = 1.f / (s + 1e-6f);
    // pack p -> bf16 pairs: pkk[a][c] covers p[c*4 .. c*4+3]
    unsigned int pkk[2][4][2];
#pragma unroll
    for (int a = 0; a < 2; a++)
#pragma unroll
      for (int c = 0; c < 4; c++) {
        pkk[a][c][0] = cvtpk_bf16(S[a][b][c * 4 + 0] * inv, S[a][b][c * 4 + 1] * inv);
        pkk[a][c][1] = cvtpk_bf16(S[a][b][c * 4 + 2] * inv, S[a][b][c * 4 + 3] * inv);
      }
    // PV: O[qt][d] accumulated over 4 k-steps (a x ks); A-frag built by
    // half-exchange: words0-1 = half0's block c=2ks+hi, words2-3 = half1's.
    f32x16 O = {};
#pragma unroll
    for (int a = 0; a < 2; a++)
#pragma unroll
      for (int ks = 0; ks < 2; ks++) {
        unsigned int s0 = hi ? pkk[a][2 * ks][0] : pkk[a][2 * ks + 1][0];
        unsigned int s1 = hi ? pkk[a][2 * ks][1] : pkk[a][2 * ks + 1][1];
        unsigned int r0 = __shfl_xor(s0, 32);
        unsigned int r1 = __shfl_xor(s1, 32);
        unsigned int w0 = hi ? r0 : pkk[a][2 * ks][0];
        unsigned int w1 = hi ? r1 : pkk[a][2 * ks][1];
        unsigned int w2 = hi ? pkk[a][2 * ks + 1][0] : r0;
        unsigned int w3 = hi ? pkk[a][2 * ks + 1][1] : r1;
        uint4 wq = {w0, w1, w2, w3};
        bf16x8 pa = __builtin_bit_cast(bf16x8, wq);
        bf16x8 vb = *reinterpret_cast<const bf16x8*>(&Vt[wv][l31][a * 32 + ks * 16 + hi * 8]);
        O = __builtin_amdgcn_mfma_f32_32x32x16_bf16(pa, vb, O, 0, 0, 0);
      }
    // store: O col = d = l31, row = b*32 + crow(r,hi)
#pragma unroll
    for (int r = 0; r < 16; r++) {
      int qrow = b * 32 + (r & 3) + 8 * (r >> 2) + 4 * hi;
      if (qrow < 49)
        attn[(rowbase + qrow) * 384 + h * 32 + l31] = f2bf(O[r]);
    }
  }
}

// ------------------------------------------------------ K2b: proj GEMM ----
// R6 inner structure with in-block n-serialization over the 3 n-tiles.
__global__ void __launch_bounds__(256, 4) k_proj(const ushort_t* __restrict__ a,
                                                 const ushort_t* __restrict__ wb,
                                                 const float* __restrict__ pbias,
                                                 float* __restrict__ out, int nmb) {
  __shared__ __align__(16) ushort_t As[128][64];
  __shared__ __align__(16) ushort_t Bs[128][64];
  const int tid = threadIdx.x;
  const int lane = tid & 63, wid = tid >> 6;
  const int wm = wid >> 1, wn = wid & 1;
  const int l15 = lane & 15, g = lane >> 4;
  const int mblk = xcd_swz(blockIdx.x, nmb);
  const int m0 = mblk * 128;

  const int rb_ = (wid << 3) + (lane >> 3);
  const int cg_ = (lane & 7) ^ (rb_ & 7);
  const size_t so_ = (size_t)rb_ * 384 + cg_ * 8;
  const int lo_ = wid * 512;

#define PRJ_STAGE(n0v, kk)                                                   \
  {                                                                          \
    const ushort_t* ga = a + (size_t)m0 * 384 + (kk) * 64;                   \
    const ushort_t* gb = wb + (size_t)(n0v) * 384 + (kk) * 64;               \
    _Pragma("unroll")                                                        \
    for (int it = 0; it < 4; it++) {                                         \
      gload_lds16(ga + so_ + (size_t)it * 12288, &As[0][0] + lo_ + it * 2048);\
      gload_lds16(gb + so_ + (size_t)it * 12288, &Bs[0][0] + lo_ + it * 2048);\
    }                                                                        \
  }

  for (int nt = 0; nt < 3; nt++) {
    const int n0 = nt * 128;
    f32x4 acc[4][4] = {};
    for (int kk = 0; kk < 6; kk++) {
      __syncthreads();
      PRJ_STAGE(n0, kk);
      __syncthreads();
#pragma unroll
      for (int ks = 0; ks < 64; ks += 32) {
        const int cxor = (ks >> 3) + g;
        bf16x8 av[4], bv[4];
#pragma unroll
        for (int mi = 0; mi < 4; mi++) {
          int row = wm * 64 + mi * 16 + l15;
          av[mi] = *reinterpret_cast<const bf16x8*>(&As[row][(cxor ^ (row & 7)) * 8]);
        }
#pragma unroll
        for (int ni = 0; ni < 4; ni++) {
          int row = wn * 64 + ni * 16 + l15;
          bv[ni] = *reinterpret_cast<const bf16x8*>(&Bs[row][(cxor ^ (row & 7)) * 8]);
        }
#pragma unroll
        for (int mi = 0; mi < 4; mi++)
#pragma unroll
          for (int ni = 0; ni < 4; ni++)
            acc[mi][ni] = __builtin_amdgcn_mfma_f32_16x16x32_bf16(av[mi], bv[ni], acc[mi][ni], 0, 0, 0);
      }
    }
    const int colbase = n0 + wn * 64;
    float bs[4];
#pragma unroll
    for (int ni = 0; ni < 4; ni++) bs[ni] = pbias[colbase + ni * 16 + l15];
#pragma unroll
    for (int mi = 0; mi < 4; mi++)
#pragma unroll
      for (int r = 0; r < 4; r++) {
        int row = m0 + wm * 64 + mi * 16 + g * 4 + r;
#pragma unroll
        for (int ni = 0; ni < 4; ni++)
          out[(size_t)row * 384 + colbase + ni * 16 + l15] = acc[mi][ni][r] + bs[ni];
      }
  }
#undef PRJ_STAGE
}

// ------------------------------------------------------------- launch ----
extern "C" void kernel_launch(void* const* d_in, const int* in_sizes, int n_in,
                              void* d_out, int out_size, void* d_ws, size_t ws_size,
                              hipStream_t stream) {
  const float* x        = (const float*)d_in[0];
  const float* mask     = (const float*)d_in[1];
  const float* qkv_w    = (const float*)d_in[2];
  const float* q_bias   = (const float*)d_in[3];
  const float* v_bias   = (const float*)d_in[4];
  const float* logit_sc = (const float*)d_in[5];
  const float* cpb_w1   = (const float*)d_in[6];
  const float* cpb_b1   = (const float*)d_in[7];
  const float* cpb_w2   = (const float*)d_in[8];
  const float* proj_w   = (const float*)d_in[9];
  const float* proj_b   = (const float*)d_in[10];
  const float* rel_tab  = (const float*)d_in[11];
  const int*   rel_idx  = (const int*)d_in[12];
  float* out = (float*)d_out;

  char* p = (char*)d_ws;
  auto carve = [&](size_t bytes) { char* r = p; p += (bytes + 255) & ~(size_t)255; return r; };
  ushort_t* qkv_wb  = (ushort_t*)carve(1152 * 384 * 2);
  ushort_t* proj_wb = (ushort_t*)carve(384 * 384 * 2);
  float* qkv_bias   = (float*)carve(1152 * 4);
  float* tbl        = (float*)carve(169 * 12 * 4);
  float* lsb        = (float*)carve(12 * 4);
  float* comb       = (float*)carve((size_t)64 * 12 * 2404 * 4);
  size_t fixed = (size_t)(p - (char*)d_ws);
  size_t avail = ws_size > fixed ? ws_size - fixed : 0;

  int nc = 1;
  while (nc < 16) {
    size_t per = ((size_t)(2048 / nc)) * 49 * (384 + 1152 + 384) * 2 + (1 << 20);
    if (per <= avail) break;
    nc *= 2;
  }
  const int nwin = 2048 / nc;
  const size_t Mc = (size_t)nwin * 49;
  ushort_t* xbuf  = (ushort_t*)carve(Mc * 384 * 2);
  ushort_t* qkvn  = (ushort_t*)carve(Mc * 1152 * 2);
  ushort_t* attnb = (ushort_t*)carve(Mc * 384 * 2);
  const int nmb = (int)(Mc / 128);
  const int nk = nwin >> 6;                 // windows per (w) residue per chunk

  k_prep_w<<<dim3(512), dim3(256), 0, stream>>>(qkv_w, proj_w, q_bias, v_bias, qkv_wb, proj_wb, qkv_bias);
  k_prep_cpb<<<dim3(170), dim3(64), 0, stream>>>(rel_tab, cpb_w1, cpb_b1, cpb_w2, logit_sc, tbl, lsb);
  k_prep_comb<<<dim3((64 * 12 * 2401 + 255) / 256), dim3(256), 0, stream>>>(tbl, rel_idx, mask, comb);

  for (int c = 0; c < nc; c++) {
    size_t roff = (size_t)c * Mc;
    k_xb<<<dim3(2048), dim3(256), 0, stream>>>(x + roff * 384, xbuf, (long)(Mc * 384 / 4));
    k_qkv<<<dim3(nmb), dim3(256), 0, stream>>>(xbuf, qkv_wb, qkv_bias, lsb, qkvn, nmb);
    k_attn<<<dim3(64 * ((nk + 3) / 4), 12), dim3(256), 0, stream>>>(qkvn, comb, attnb, c * nwin, nk);
    k_proj<<<dim3(nmb), dim3(256), 0, stream>>>(attnb, proj_wb, proj_b, out + roff * 384, nmb);
  }
}

// Round 17
// 386.186 us; speedup vs baseline: 1.4055x; 1.4055x over previous
//
#include <hip/hip_runtime.h>
#include <hip/hip_bf16.h>

typedef __attribute__((ext_vector_type(8))) short bf16x8;
typedef __attribute__((ext_vector_type(4))) float f32x4;
typedef __attribute__((ext_vector_type(16))) float f32x16;
typedef __attribute__((ext_vector_type(8))) unsigned short u16x8;
typedef unsigned short ushort_t;

#define DEVFN static __device__ __forceinline__

DEVFN ushort_t f2bf(float f) {
  unsigned int u = __builtin_bit_cast(unsigned int, f);
  u += 0x7FFFu + ((u >> 16) & 1u);   // RNE
  return (ushort_t)(u >> 16);
}

DEVFN unsigned int cvtpk_bf16(float lo, float hi) {
  unsigned int r;
  asm("v_cvt_pk_bf16_f32 %0, %1, %2" : "=v"(r) : "v"(lo), "v"(hi));
  return r;
}

// async global->LDS, 16B per lane; LDS dest is wave-uniform base + lane*16
DEVFN void gload_lds16(const void* g, void* l) {
  __builtin_amdgcn_global_load_lds(
      (const __attribute__((address_space(1))) void*)g,
      (__attribute__((address_space(3))) void*)l, 16, 0, 0);
}

// bijective XCD swizzle (m204): consecutive post-swizzle ids share an XCD
DEVFN int xcd_swz(int bid, int nwg) {
  int q = nwg >> 3, r = nwg & 7;
  int xcd = bid & 7, u = bid >> 3;
  return (xcd < r ? xcd * (q + 1) : r * (q + 1) + (xcd - r) * q) + u;
}

// ---------------------------------------------------------------- prep ----
__global__ void k_prep_w(const float* __restrict__ qkv_w, const float* __restrict__ proj_w,
                         const float* __restrict__ q_bias, const float* __restrict__ v_bias,
                         ushort_t* __restrict__ qkv_wb, ushort_t* __restrict__ proj_wb,
                         float* __restrict__ qkv_bias) {
  int gid = blockIdx.x * blockDim.x + threadIdx.x;
  int stride = gridDim.x * blockDim.x;
  for (int i = gid; i < 1152 * 384; i += stride) qkv_wb[i] = f2bf(qkv_w[i]);
  for (int i = gid; i < 384 * 384; i += stride) proj_wb[i] = f2bf(proj_w[i]);
  for (int i = gid; i < 1152; i += stride)
    qkv_bias[i] = (i < 384) ? q_bias[i] : ((i < 768) ? 0.f : v_bias[i - 768]);
}

// x (fp32) -> bf16, vectorized
__global__ void k_xb(const float* __restrict__ x, ushort_t* __restrict__ xb, long n4) {
  long gid = (long)blockIdx.x * blockDim.x + threadIdx.x;
  long stride = (long)gridDim.x * blockDim.x;
  for (long i = gid; i < n4; i += stride) {
    float4 v = reinterpret_cast<const float4*>(x)[i];
    unsigned long long pk = (unsigned long long)f2bf(v.x) |
                            ((unsigned long long)f2bf(v.y) << 16) |
                            ((unsigned long long)f2bf(v.z) << 32) |
                            ((unsigned long long)f2bf(v.w) << 48);
    reinterpret_cast<unsigned long long*>(xb)[i] = pk;
  }
}

// CPB MLP: one block (64 threads) per table row; block 169 does logit scales
__global__ void k_prep_cpb(const float* __restrict__ rel_table, const float* __restrict__ cpb_w1,
                           const float* __restrict__ cpb_b1, const float* __restrict__ cpb_w2,
                           const float* __restrict__ logit_scale,
                           float* __restrict__ tbl, float* __restrict__ ls) {
  int lane = threadIdx.x;
  if (blockIdx.x == 169) {
    if (lane < 12) ls[lane] = __expf(fminf(logit_scale[lane], 4.605170185988092f)); // log(100)
    return;
  }
  int row = blockIdx.x;
  float t0 = rel_table[row * 2 + 0], t1 = rel_table[row * 2 + 1];
  float acc[12];
#pragma unroll
  for (int h = 0; h < 12; h++) acc[h] = 0.f;
  for (int j = lane; j < 512; j += 64) {
    float hj = fmaxf(cpb_w1[j * 2] * t0 + cpb_w1[j * 2 + 1] * t1 + cpb_b1[j], 0.f);
#pragma unroll
    for (int h = 0; h < 12; h++) acc[h] += cpb_w2[h * 512 + j] * hj;
  }
#pragma unroll
  for (int h = 0; h < 12; h++) {
    float v = acc[h];
    v += __shfl_xor(v, 1);  v += __shfl_xor(v, 2);  v += __shfl_xor(v, 4);
    v += __shfl_xor(v, 8);  v += __shfl_xor(v, 16); v += __shfl_xor(v, 32);
    if (lane == 0) tbl[row * 12 + h] = v;
  }
}

// comb[(w*12+h)*2404 + i*49+j] = 16*sigmoid(tbl[rel_index[ij]][h]) + mask[w][ij]
__global__ void k_prep_comb(const float* __restrict__ tbl, const int* __restrict__ rel_index,
                            const float* __restrict__ mask, float* __restrict__ comb) {
  int gid = blockIdx.x * blockDim.x + threadIdx.x;
  if (gid >= 64 * 12 * 2401) return;
  int ij = gid % 2401;
  int h = (gid / 2401) % 12;
  int w = gid / (2401 * 12);
  float t = tbl[rel_index[ij] * 12 + h];
  comb[(size_t)(w * 12 + h) * 2404 + ij] = 16.f / (1.f + __expf(-t)) + mask[w * 2401 + ij];
}

// ------------------------------------------------- K1: qkv GEMM + norm ----
// C[M x 1152] = xb[M x 384] * qkv_w^T (bf16 in), + bias; q rows L2-normalized
// AND scaled by per-head logit scale; k rows L2-normalized. bf16 out.
// R6-proven structure: 2x2 waves 64x64, 32 KB single-buffer LDS,
// gload_lds + XOR swizzle, XCD-swizzled grid (n-fastest for A-sharing).
__global__ void __launch_bounds__(256, 4) k_qkv(const ushort_t* __restrict__ xb,
                                                const ushort_t* __restrict__ wb,
                                                const float* __restrict__ bias,
                                                const float* __restrict__ lsb,
                                                ushort_t* __restrict__ qkvn, int nmb) {
  __shared__ __align__(16) ushort_t As[128][64];
  __shared__ __align__(16) ushort_t Bs[128][64];
  const int tid = threadIdx.x;
  const int lane = tid & 63, wid = tid >> 6;
  const int wm = wid >> 1, wn = wid & 1;   // 2 x 2 wave grid, each 64 x 64
  const int l15 = lane & 15, g = lane >> 4;
  const int t = xcd_swz(blockIdx.x, nmb * 9);
  const int m0 = (t / 9) * 128, n0 = (t % 9) * 128;
  f32x4 acc[4][4] = {};

  // staging geometry (loop-invariant): chunk i = wid*64 + lane + it*256
  const int rb_ = (wid << 3) + (lane >> 3);           // row base (it=0)
  const int cg_ = (lane & 7) ^ (rb_ & 7);             // pre-swizzled src chunk
  const size_t so_ = (size_t)rb_ * 384 + cg_ * 8;
  const int lo_ = wid * 512;                          // wave-uniform LDS base

#define QKV_STAGE(kk)                                                        \
  {                                                                          \
    const ushort_t* ga = xb + (size_t)m0 * 384 + (kk) * 64;                  \
    const ushort_t* gb = wb + (size_t)n0 * 384 + (kk) * 64;                  \
    _Pragma("unroll")                                                        \
    for (int it = 0; it < 4; it++) {                                         \
      gload_lds16(ga + so_ + (size_t)it * 12288, &As[0][0] + lo_ + it * 2048);\
      gload_lds16(gb + so_ + (size_t)it * 12288, &Bs[0][0] + lo_ + it * 2048);\
    }                                                                        \
  }

  for (int kk = 0; kk < 6; kk++) {
    __syncthreads();
    QKV_STAGE(kk);
    __syncthreads();
#pragma unroll
    for (int ks = 0; ks < 64; ks += 32) {
      const int cxor = (ks >> 3) + g;
      bf16x8 a[4], b[4];
#pragma unroll
      for (int mi = 0; mi < 4; mi++) {
        int row = wm * 64 + mi * 16 + l15;
        a[mi] = *reinterpret_cast<const bf16x8*>(&As[row][(cxor ^ (row & 7)) * 8]);
      }
#pragma unroll
      for (int ni = 0; ni < 4; ni++) {
        int row = wn * 64 + ni * 16 + l15;
        b[ni] = *reinterpret_cast<const bf16x8*>(&Bs[row][(cxor ^ (row & 7)) * 8]);
      }
#pragma unroll
      for (int mi = 0; mi < 4; mi++)
#pragma unroll
        for (int ni = 0; ni < 4; ni++)
          acc[mi][ni] = __builtin_amdgcn_mfma_f32_16x16x32_bf16(a[mi], b[ni], acc[mi][ni], 0, 0, 0);
    }
  }
#undef QKV_STAGE
  // epilogue: bias, per-32-col head-group L2 norm (q also * logit scale)
  const int colbase = n0 + wn * 64;          // 64-aligned: never crosses q/k/v
  const int which = colbase / 384;           // 0=q 1=k 2=v
  const float scl0 = (which == 0) ? lsb[(colbase >> 5)] : 1.f;
  const float scl1 = (which == 0) ? lsb[(colbase >> 5) + 1] : 1.f;
  float bs[4];
#pragma unroll
  for (int ni = 0; ni < 4; ni++) bs[ni] = bias[colbase + ni * 16 + l15];
#pragma unroll
  for (int mi = 0; mi < 4; mi++) {
#pragma unroll
    for (int r = 0; r < 4; r++) {
      float v[4];
#pragma unroll
      for (int ni = 0; ni < 4; ni++) v[ni] = acc[mi][ni][r] + bs[ni];
      if (which < 2) {
        float ss0 = v[0] * v[0] + v[1] * v[1];
        float ss1 = v[2] * v[2] + v[3] * v[3];
        ss0 += __shfl_xor(ss0, 1); ss1 += __shfl_xor(ss1, 1);
        ss0 += __shfl_xor(ss0, 2); ss1 += __shfl_xor(ss1, 2);
        ss0 += __shfl_xor(ss0, 4); ss1 += __shfl_xor(ss1, 4);
        ss0 += __shfl_xor(ss0, 8); ss1 += __shfl_xor(ss1, 8);
        float rn0 = scl0 / (sqrtf(ss0) + 1e-6f);
        float rn1 = scl1 / (sqrtf(ss1) + 1e-6f);
        v[0] *= rn0; v[1] *= rn0; v[2] *= rn1; v[3] *= rn1;
      }
      int row = m0 + wm * 64 + mi * 16 + g * 4 + r;
      size_t base = (size_t)row * 1152 + colbase + l15;
#pragma unroll
      for (int ni = 0; ni < 4; ni++) qkvn[base + ni * 16] = f2bf(v[ni]);
    }
  }
}

// ------------------------------------------- K2a: attention per (win,h) ----
// 4-wave blocks; waves handle 4 windows sharing the same shift-window w.
// ILP: all global loads issued before comb staging; comb in padded [50][52]
// LDS (ds_read_b128 bias adds); float4 comb staging (stride-2404 source).
__global__ void __launch_bounds__(256, 4) k_attn(const ushort_t* __restrict__ qkvn,
                                                 const float* __restrict__ comb,
                                                 ushort_t* __restrict__ attn,
                                                 int win_base, int nk) {
  __shared__ __align__(16) float comb_s[50][52];
  __shared__ __align__(16) ushort_t Vt[4][32][72];
  const int tid = threadIdx.x;
  const int lane = tid & 63, wv = tid >> 6;
  const int l31 = lane & 31, hi = lane >> 5;
  const int h = blockIdx.y;
  const int wloc = blockIdx.x & 63;
  const int k = (blockIdx.x >> 6) * 4 + wv;
  const bool active = k < nk;
  const int w_abs = (win_base + wloc) & 63;
  const size_t rowbase = (size_t)(wloc + 64 * k) * 49;

  // ---- issue ALL global loads first (ILP: ~12x16B in flight per lane) ----
  u16x8 vreg[4];
  bf16x8 qf[2][2], kf[2][2];
  if (active) {
#pragma unroll
    for (int pass = 0; pass < 4; pass++) {
      int t = pass * 16 + (lane >> 2);
      int d0 = (lane & 3) * 8;
      u16x8 v = {};
      if (t < 49)
        v = *reinterpret_cast<const u16x8*>(&qkvn[(rowbase + t) * 1152 + 768 + h * 32 + d0]);
      vreg[pass] = v;
    }
#pragma unroll
    for (int b = 0; b < 2; b++) {
      int t = b * 32 + l31; if (t > 48) t = 48;
      size_t rb = (rowbase + t) * 1152 + h * 32 + hi * 8;
#pragma unroll
      for (int ks = 0; ks < 2; ks++) {
        qf[b][ks] = *reinterpret_cast<const bf16x8*>(&qkvn[rb + ks * 16]);
        kf[b][ks] = *reinterpret_cast<const bf16x8*>(&qkvn[rb + 384 + ks * 16]);
      }
    }
  }

  // ---- comb stage: float4 global loads, scatter into padded layout ----
  {
    const float* ct = comb + (size_t)(w_abs * 12 + h) * 2404;
    for (int i4 = tid; i4 < 600; i4 += 256) {
      float4 v = *reinterpret_cast<const float4*>(&ct[i4 * 4]);
      int e = i4 * 4;
      comb_s[(e + 0) / 49][(e + 0) % 49] = v.x;
      comb_s[(e + 1) / 49][(e + 1) % 49] = v.y;
      comb_s[(e + 2) / 49][(e + 2) % 49] = v.z;
      comb_s[(e + 3) / 49][(e + 3) % 49] = v.w;
    }
    if (tid == 0) comb_s[48][48] = ct[2400];
  }
  // ---- Vt LDS writes (waitcnt for vreg hides under comb staging) ----
  if (active) {
#pragma unroll
    for (int pass = 0; pass < 4; pass++) {
      int t = pass * 16 + (lane >> 2);
      int d0 = (lane & 3) * 8;
#pragma unroll
      for (int j = 0; j < 8; j++) Vt[wv][d0 + j][t] = vreg[pass][j];
    }
  }
  __syncthreads();
  if (!active) return;

  // S'[a][b] = K_a · Q_b^T : lane owns col qt = b*32+l31, rows kt = a*32+crow(r,hi)
  f32x16 S[2][2] = {};
#pragma unroll
  for (int a = 0; a < 2; a++)
#pragma unroll
    for (int b = 0; b < 2; b++) {
      S[a][b] = __builtin_amdgcn_mfma_f32_32x32x16_bf16(kf[a][0], qf[b][0], S[a][b], 0, 0, 0);
      S[a][b] = __builtin_amdgcn_mfma_f32_32x32x16_bf16(kf[a][1], qf[b][1], S[a][b], 0, 0, 0);
    }

#pragma unroll
  for (int b = 0; b < 2; b++) {
    const int qt = b * 32 + l31;
    const bool qok = qt < 49;
    const int qi = qok ? qt : 48;
    // bias add + mask + row max; comb read as f32x4 (rows 16B-aligned)
    float m = -3.0e38f;
#pragma unroll
    for (int a = 0; a < 2; a++)
#pragma unroll
      for (int rq = 0; rq < 4; rq++) {
        f32x4 ch = *reinterpret_cast<const f32x4*>(&comb_s[qi][a * 32 + rq * 8 + hi * 4]);
#pragma unroll
        for (int j = 0; j < 4; j++) {
          int r = rq * 4 + j;
          int kt = a * 32 + rq * 8 + hi * 4 + j;
          float v = (qok && kt < 49) ? (S[a][b][r] + ch[j]) : -3.0e38f;
          S[a][b][r] = v;
          m = fmaxf(m, v);
        }
      }
    m = fmaxf(m, __shfl_xor(m, 32));
    float s = 0.f;
#pragma unroll
    for (int a = 0; a < 2; a++)
#pragma unroll
      for (int r = 0; r < 16; r++) {
        float e = __expf(S[a][b][r] - m);
        S[a][b][r] = e;
        s += e;
      }
    s += __shfl_xor(s, 32);
    const float inv = 1.f / (s + 1e-6f);
    // pack p -> bf16 pairs: pkk[a][c] covers p[c*4 .. c*4+3]
    unsigned int pkk[2][4][2];
#pragma unroll
    for (int a = 0; a < 2; a++)
#pragma unroll
      for (int c = 0; c < 4; c++) {
        pkk[a][c][0] = cvtpk_bf16(S[a][b][c * 4 + 0] * inv, S[a][b][c * 4 + 1] * inv);
        pkk[a][c][1] = cvtpk_bf16(S[a][b][c * 4 + 2] * inv, S[a][b][c * 4 + 3] * inv);
      }
    // PV: O[qt][d] accumulated over 4 k-steps (a x ks); A-frag built by
    // half-exchange: words0-1 = half0's block c=2ks+hi, words2-3 = half1's.
    f32x16 O = {};
#pragma unroll
    for (int a = 0; a < 2; a++)
#pragma unroll
      for (int ks = 0; ks < 2; ks++) {
        unsigned int s0 = hi ? pkk[a][2 * ks][0] : pkk[a][2 * ks + 1][0];
        unsigned int s1 = hi ? pkk[a][2 * ks][1] : pkk[a][2 * ks + 1][1];
        unsigned int r0 = __shfl_xor(s0, 32);
        unsigned int r1 = __shfl_xor(s1, 32);
        unsigned int w0 = hi ? r0 : pkk[a][2 * ks][0];
        unsigned int w1 = hi ? r1 : pkk[a][2 * ks][1];
        unsigned int w2 = hi ? pkk[a][2 * ks + 1][0] : r0;
        unsigned int w3 = hi ? pkk[a][2 * ks + 1][1] : r1;
        uint4 wq = {w0, w1, w2, w3};
        bf16x8 pa = __builtin_bit_cast(bf16x8, wq);
        bf16x8 vb = *reinterpret_cast<const bf16x8*>(&Vt[wv][l31][a * 32 + ks * 16 + hi * 8]);
        O = __builtin_amdgcn_mfma_f32_32x32x16_bf16(pa, vb, O, 0, 0, 0);
      }
    // store: O col = d = l31, row = b*32 + crow(r,hi)
#pragma unroll
    for (int r = 0; r < 16; r++) {
      int qrow = b * 32 + (r & 3) + 8 * (r >> 2) + 4 * hi;
      if (qrow < 49)
        attn[(rowbase + qrow) * 384 + h * 32 + l31] = f2bf(O[r]);
    }
  }
}

// ------------------------------------------------------ K2b: proj GEMM ----
// R6-proven 2x2-wave 64x64 LDS structure.
__global__ void __launch_bounds__(256, 4) k_proj(const ushort_t* __restrict__ a,
                                                 const ushort_t* __restrict__ wb,
                                                 const float* __restrict__ pbias,
                                                 float* __restrict__ out, int nmb) {
  __shared__ __align__(16) ushort_t As[128][64];
  __shared__ __align__(16) ushort_t Bs[128][64];
  const int tid = threadIdx.x;
  const int lane = tid & 63, wid = tid >> 6;
  const int wm = wid >> 1, wn = wid & 1;
  const int l15 = lane & 15, g = lane >> 4;
  const int t = xcd_swz(blockIdx.x, nmb * 3);
  const int m0 = (t / 3) * 128, n0 = (t % 3) * 128;
  f32x4 acc[4][4] = {};

  const int rb_ = (wid << 3) + (lane >> 3);
  const int cg_ = (lane & 7) ^ (rb_ & 7);
  const size_t so_ = (size_t)rb_ * 384 + cg_ * 8;
  const int lo_ = wid * 512;

#define PRJ_STAGE(kk)                                                        \
  {                                                                          \
    const ushort_t* ga = a + (size_t)m0 * 384 + (kk) * 64;                   \
    const ushort_t* gb = wb + (size_t)n0 * 384 + (kk) * 64;                  \
    _Pragma("unroll")                                                        \
    for (int it = 0; it < 4; it++) {                                         \
      gload_lds16(ga + so_ + (size_t)it * 12288, &As[0][0] + lo_ + it * 2048);\
      gload_lds16(gb + so_ + (size_t)it * 12288, &Bs[0][0] + lo_ + it * 2048);\
    }                                                                        \
  }

  for (int kk = 0; kk < 6; kk++) {
    __syncthreads();
    PRJ_STAGE(kk);
    __syncthreads();
#pragma unroll
    for (int ks = 0; ks < 64; ks += 32) {
      const int cxor = (ks >> 3) + g;
      bf16x8 av[4], bv[4];
#pragma unroll
      for (int mi = 0; mi < 4; mi++) {
        int row = wm * 64 + mi * 16 + l15;
        av[mi] = *reinterpret_cast<const bf16x8*>(&As[row][(cxor ^ (row & 7)) * 8]);
      }
#pragma unroll
      for (int ni = 0; ni < 4; ni++) {
        int row = wn * 64 + ni * 16 + l15;
        bv[ni] = *reinterpret_cast<const bf16x8*>(&Bs[row][(cxor ^ (row & 7)) * 8]);
      }
#pragma unroll
      for (int mi = 0; mi < 4; mi++)
#pragma unroll
        for (int ni = 0; ni < 4; ni++)
          acc[mi][ni] = __builtin_amdgcn_mfma_f32_16x16x32_bf16(av[mi], bv[ni], acc[mi][ni], 0, 0, 0);
    }
  }
#undef PRJ_STAGE
  const int colbase = n0 + wn * 64;
  float bs[4];
#pragma unroll
  for (int ni = 0; ni < 4; ni++) bs[ni] = pbias[colbase + ni * 16 + l15];
#pragma unroll
  for (int mi = 0; mi < 4; mi++)
#pragma unroll
    for (int r = 0; r < 4; r++) {
      int row = m0 + wm * 64 + mi * 16 + g * 4 + r;
#pragma unroll
      for (int ni = 0; ni < 4; ni++)
        out[(size_t)row * 384 + colbase + ni * 16 + l15] = acc[mi][ni][r] + bs[ni];
    }
}

// ------------------------------------------------------------- launch ----
extern "C" void kernel_launch(void* const* d_in, const int* in_sizes, int n_in,
                              void* d_out, int out_size, void* d_ws, size_t ws_size,
                              hipStream_t stream) {
  const float* x        = (const float*)d_in[0];
  const float* mask     = (const float*)d_in[1];
  const float* qkv_w    = (const float*)d_in[2];
  const float* q_bias   = (const float*)d_in[3];
  const float* v_bias   = (const float*)d_in[4];
  const float* logit_sc = (const float*)d_in[5];
  const float* cpb_w1   = (const float*)d_in[6];
  const float* cpb_b1   = (const float*)d_in[7];
  const float* cpb_w2   = (const float*)d_in[8];
  const float* proj_w   = (const float*)d_in[9];
  const float* proj_b   = (const float*)d_in[10];
  const float* rel_tab  = (const float*)d_in[11];
  const int*   rel_idx  = (const int*)d_in[12];
  float* out = (float*)d_out;

  char* p = (char*)d_ws;
  auto carve = [&](size_t bytes) { char* r = p; p += (bytes + 255) & ~(size_t)255; return r; };
  ushort_t* qkv_wb  = (ushort_t*)carve(1152 * 384 * 2);
  ushort_t* proj_wb = (ushort_t*)carve(384 * 384 * 2);
  float* qkv_bias   = (float*)carve(1152 * 4);
  float* tbl        = (float*)carve(169 * 12 * 4);
  float* lsb        = (float*)carve(12 * 4);
  float* comb       = (float*)carve((size_t)64 * 12 * 2404 * 4);
  size_t fixed = (size_t)(p - (char*)d_ws);
  size_t avail = ws_size > fixed ? ws_size - fixed : 0;

  int nc = 1;
  while (nc < 16) {
    size_t per = ((size_t)(2048 / nc)) * 49 * (384 + 1152 + 384) * 2 + (1 << 20);
    if (per <= avail) break;
    nc *= 2;
  }
  const int nwin = 2048 / nc;
  const size_t Mc = (size_t)nwin * 49;
  ushort_t* xbuf  = (ushort_t*)carve(Mc * 384 * 2);
  ushort_t* qkvn  = (ushort_t*)carve(Mc * 1152 * 2);
  ushort_t* attnb = (ushort_t*)carve(Mc * 384 * 2);
  const int nmb = (int)(Mc / 128);
  const int nk = nwin >> 6;                 // windows per (w) residue per chunk

  k_prep_w<<<dim3(512), dim3(256), 0, stream>>>(qkv_w, proj_w, q_bias, v_bias, qkv_wb, proj_wb, qkv_bias);
  k_prep_cpb<<<dim3(170), dim3(64), 0, stream>>>(rel_tab, cpb_w1, cpb_b1, cpb_w2, logit_sc, tbl, lsb);
  k_prep_comb<<<dim3((64 * 12 * 2401 + 255) / 256), dim3(256), 0, stream>>>(tbl, rel_idx, mask, comb);

  for (int c = 0; c < nc; c++) {
    size_t roff = (size_t)c * Mc;
    k_xb<<<dim3(2048), dim3(256), 0, stream>>>(x + roff * 384, xbuf, (long)(Mc * 384 / 4));
    k_qkv<<<dim3(nmb * 9), dim3(256), 0, stream>>>(xbuf, qkv_wb, qkv_bias, lsb, qkvn, nmb);
    k_attn<<<dim3(64 * ((nk + 3) / 4), 12), dim3(256), 0, stream>>>(qkvn, comb, attnb, c * nwin, nk);
    k_proj<<<dim3(nmb * 3), dim3(256), 0, stream>>>(attnb, proj_wb, proj_b, out + roff * 384, nmb);
  }
}